// Round 11
// baseline (431.552 us; speedup 1.0000x reference)
//
#include <hip/hip_runtime.h>
#include <hip/hip_bf16.h>

#define GROUPS 32
#define EPS_GN 1e-5f

typedef short bf16x8 __attribute__((ext_vector_type(8)));
typedef float f32x4 __attribute__((ext_vector_type(4)));

__device__ __forceinline__ ushort to_bf16_bits(float v) {
  __hip_bfloat16 h = __float2bfloat16(v);
  return *(ushort*)&h;
}
__device__ __forceinline__ float bflo(unsigned u) { return __uint_as_float(u << 16); }
__device__ __forceinline__ float bfhi(unsigned u) { return __uint_as_float(u & 0xffff0000u); }
__device__ __forceinline__ ushort bfpack(float f) {
  return (ushort)(__float_as_uint(f) >> 16);   // exact: values originate from bf16
}

// ---------------- weight cast f32 [O][K] -> bf16 [O][Kp] (zero pad K..Kp) --------
__global__ __launch_bounds__(256)
void cast_w_kernel(const float* __restrict__ w, ushort* __restrict__ wb,
                   int K, int Kp, int total)
{
  int idx = blockIdx.x * 256 + threadIdx.x;
  if (idx >= total) return;
  int o = idx / Kp, k = idx - o * Kp;
  float v = (k < K) ? w[(size_t)o * K + k] : 0.f;
  wb[idx] = to_bf16_bits(v);
}

// ------- transpose+cast with offset: f32 [B][C][T] -> bf16 dst[b][t][coff+c] -----
__global__ __launch_bounds__(256)
void transpose_cast_off(const float* __restrict__ src, ushort* __restrict__ dst,
                        int C, int T, int dstride, int coff, int Cpad)
{
  __shared__ float tile[32][33];
  const int b = blockIdx.z;
  const int c0 = blockIdx.y * 32, t0 = blockIdx.x * 32;
  const int tx = threadIdx.x & 31, ty = threadIdx.x >> 5;   // 32 x 8
#pragma unroll
  for (int i = 0; i < 4; ++i) {
    const int c = c0 + ty + 8 * i;
    tile[ty + 8 * i][tx] = (c < C) ? src[((size_t)b * C + c) * T + t0 + tx] : 0.f;
  }
  __syncthreads();
  const int cw = c0 + tx;
  if (cw >= Cpad) return;
#pragma unroll
  for (int i = 0; i < 4; ++i)
    dst[((size_t)b * T + t0 + ty + 8 * i) * dstride + coff + cw] =
        to_bf16_bits(tile[tx][ty + 8 * i]);
}

// ---- generic row-group maxima: dst[rt][c] = max over `rows` consecutive src rows --
__global__ __launch_bounds__(256)
void bmx_reduce(const ushort* __restrict__ src, ushort* __restrict__ dst,
                int C, int rows, int total8)
{
  int idx = blockIdx.x * 256 + threadIdx.x;
  if (idx >= total8) return;
  const int nc8 = C >> 3;
  const int ci = idx % nc8;
  const int rt = idx / nc8;
  const ushort* p = src + (size_t)rt * rows * C + ci * 8;
  float m[8];
#pragma unroll
  for (int i = 0; i < 8; ++i) m[i] = -3.402823466e38f;
  for (int j = 0; j < rows; ++j) {
    const uint4 v = *(const uint4*)(p + (size_t)j * C);
    m[0] = fmaxf(m[0], bflo(v.x)); m[1] = fmaxf(m[1], bfhi(v.x));
    m[2] = fmaxf(m[2], bflo(v.y)); m[3] = fmaxf(m[3], bfhi(v.y));
    m[4] = fmaxf(m[4], bflo(v.z)); m[5] = fmaxf(m[5], bfhi(v.z));
    m[6] = fmaxf(m[6], bflo(v.w)); m[7] = fmaxf(m[7], bfhi(v.w));
  }
  uint4 o;
  o.x = (unsigned)bfpack(m[0]) | ((unsigned)bfpack(m[1]) << 16);
  o.y = (unsigned)bfpack(m[2]) | ((unsigned)bfpack(m[3]) << 16);
  o.z = (unsigned)bfpack(m[4]) | ((unsigned)bfpack(m[5]) << 16);
  o.w = (unsigned)bfpack(m[6]) | ((unsigned)bfpack(m[7]) << 16);
  *(uint4*)(dst + (size_t)rt * C + ci * 8) = o;
}

// ------- transposed boundary max pool with 2-level tables (8- and 32-blocks) ------
template<int CHL>
__global__ __launch_bounds__(256)
void pool_t_kernel(const ushort* __restrict__ xt, const ushort* __restrict__ bx32,
                   const ushort* __restrict__ bx8, const float* __restrict__ segs,
                   ushort* __restrict__ dst,
                   int C, int T, int TB32, int TB8, int N, int dstride, int coff)
{
  const int b    = blockIdx.z;
  const int half = blockIdx.y;
  const int n    = blockIdx.x * 4 + (threadIdx.x >> 6);
  const int lane = threadIdx.x & 63;
  const int c    = half * (C >> 1) + lane * CHL;

  const float4 sg = *(const float4*)(segs + ((size_t)b * N + n) * 4);
  const float f0 = half ? sg.z : sg.x;
  const float f1 = half ? sg.w : sg.y;
  int s = min(max((int)floorf(f0), 0), T - 1);
  int e = min(max((int)ceilf(f1), 0), T - 1);
  e = max(e, s);

  const ushort* xp  = xt  + (size_t)b * T    * C + c;
  const ushort* bp  = bx32+ (size_t)b * TB32 * C + c;
  const ushort* b8p = bx8 + (size_t)b * TB8  * C + c;

  float m[4][CHL];
#pragma unroll
  for (int u = 0; u < 4; ++u)
#pragma unroll
    for (int i = 0; i < CHL; ++i) m[u][i] = -3.402823466e38f;

  auto acc1 = [&](float* mm, const ushort* p) {
    if constexpr (CHL == 4) {
      const uint2 v = *(const uint2*)p;
      mm[0] = fmaxf(mm[0], bflo(v.x)); mm[1] = fmaxf(mm[1], bfhi(v.x));
      mm[2] = fmaxf(mm[2], bflo(v.y)); mm[3] = fmaxf(mm[3], bfhi(v.y));
    } else {
      const unsigned v = *(const unsigned*)p;
      mm[0] = fmaxf(mm[0], bflo(v)); mm[1] = fmaxf(mm[1], bfhi(v));
    }
  };
  auto scan = [&](const ushort* p, int cnt) {
    int i = 0;
    for (; i + 4 <= cnt; i += 4) {
      acc1(m[0], p);
      acc1(m[1], p + (size_t)C);
      acc1(m[2], p + 2 * (size_t)C);
      acc1(m[3], p + 3 * (size_t)C);
      p += 4 * (size_t)C;
    }
    for (; i < cnt; ++i) { acc1(m[0], p); p += (size_t)C; }
  };

  const int b0 = s >> 5, b1 = e >> 5;
  if (b0 == b1) {
    scan(xp + (size_t)s * C, e - s + 1);
  } else {
    const int t0e = (b0 + 1) << 5;
    const int a8 = (s + 7) & ~7;
    scan(xp + (size_t)s * C, a8 - s);
    scan(b8p + (size_t)(a8 >> 3) * C, (t0e - a8) >> 3);
    scan(bp + (size_t)(b0 + 1) * C, b1 - b0 - 1);
    const int r0 = b1 << 5;
    const int cnt8 = ((e + 1) >> 3) - (r0 >> 3);
    scan(b8p + (size_t)(r0 >> 3) * C, cnt8);
    const int ts = r0 + (cnt8 << 3);
    scan(xp + (size_t)ts * C, e - ts + 1);
  }

#pragma unroll
  for (int i = 0; i < CHL; ++i)
    m[0][i] = fmaxf(fmaxf(m[0][i], m[1][i]), fmaxf(m[2][i], m[3][i]));

  ushort* op = dst + ((size_t)b * N + n) * dstride + coff + c;
  if constexpr (CHL == 4) {
    uint2 o;
    o.x = (unsigned)bfpack(m[0][0]) | ((unsigned)bfpack(m[0][1]) << 16);
    o.y = (unsigned)bfpack(m[0][2]) | ((unsigned)bfpack(m[0][3]) << 16);
    *(uint2*)op = o;
  } else {
    *(unsigned*)op = (unsigned)bfpack(m[0][0]) | ((unsigned)bfpack(m[0][1]) << 16);
  }
}

// ---------------- bf16 MFMA GEMM with 2-deep register prefetch -------------------
// out[b,o,t] = sum_k W[o,k]*Xt[b,t,k] + bias[o].  REQUIRES K % 64 == 0.
// block 256 thr = 4 waves (2x2), block tile 128x128, wave tile 64x64.
__global__ __launch_bounds__(256)
void mfma_gemm(const ushort* __restrict__ Wb, const ushort* __restrict__ Xt,
               const float* __restrict__ bias, float* __restrict__ out,
               int O, int K, int T)
{
  const int b  = blockIdx.z;
  const int o0 = blockIdx.y * 128;
  const int t0 = blockIdx.x * 128;
  const int lane = threadIdx.x & 63;
  const int wid  = threadIdx.x >> 6;
  const int wm = wid >> 1, wn = wid & 1;
  const int lr = lane & 15;
  const int lq = lane >> 4;

  const ushort* wp = Wb + (size_t)(o0 + wm * 64 + lr) * K + lq * 8;
  const ushort* xp = Xt + ((size_t)b * T + t0 + wn * 64 + lr) * K + lq * 8;

  f32x4 acc[4][4];
#pragma unroll
  for (int i = 0; i < 4; ++i)
#pragma unroll
    for (int j = 0; j < 4; ++j) acc[i][j] = (f32x4){0.f, 0.f, 0.f, 0.f};

  bf16x8 a0[4], b0v[4], a1[4], b1v[4];
  // preload k=0
#pragma unroll
  for (int i = 0; i < 4; ++i) a0[i]  = *(const bf16x8*)(wp + (size_t)i * 16 * K);
#pragma unroll
  for (int j = 0; j < 4; ++j) b0v[j] = *(const bf16x8*)(xp + (size_t)j * 16 * K);

  for (int k0 = 0; k0 < K; k0 += 64) {
    // prefetch k0+32 (always in range: K % 64 == 0)
#pragma unroll
    for (int i = 0; i < 4; ++i)
      a1[i]  = *(const bf16x8*)(wp + (size_t)i * 16 * K + k0 + 32);
#pragma unroll
    for (int j = 0; j < 4; ++j)
      b1v[j] = *(const bf16x8*)(xp + (size_t)j * 16 * K + k0 + 32);
    // MFMA on set 0 (k0)
#pragma unroll
    for (int i = 0; i < 4; ++i)
#pragma unroll
      for (int j = 0; j < 4; ++j)
        acc[i][j] = __builtin_amdgcn_mfma_f32_16x16x32_bf16(a0[i], b0v[j], acc[i][j], 0, 0, 0);
    // prefetch k0+64 (next iteration's set 0)
    if (k0 + 64 < K) {
#pragma unroll
      for (int i = 0; i < 4; ++i)
        a0[i]  = *(const bf16x8*)(wp + (size_t)i * 16 * K + k0 + 64);
#pragma unroll
      for (int j = 0; j < 4; ++j)
        b0v[j] = *(const bf16x8*)(xp + (size_t)j * 16 * K + k0 + 64);
    }
    // MFMA on set 1 (k0+32)
#pragma unroll
    for (int i = 0; i < 4; ++i)
#pragma unroll
      for (int j = 0; j < 4; ++j)
        acc[i][j] = __builtin_amdgcn_mfma_f32_16x16x32_bf16(a1[i], b1v[j], acc[i][j], 0, 0, 0);
  }

#pragma unroll
  for (int i = 0; i < 4; ++i) {
#pragma unroll
    for (int r = 0; r < 4; ++r) {
      const int o = o0 + wm * 64 + i * 16 + lq * 4 + r;
      const float bs = bias[o];
      float* op = out + ((size_t)b * O + o) * T + t0 + wn * 64 + lr;
#pragma unroll
      for (int j = 0; j < 4; ++j) op[j * 16] = acc[i][j][r] + bs;
    }
  }
}

// ---------------- GroupNorm(+ReLU) in-place over [B,C,Tn] ------------------------
__global__ __launch_bounds__(256)
void gn_relu_inplace(float* __restrict__ x, const float* __restrict__ gamma,
                     const float* __restrict__ beta, int C, int Tn, int tshift)
{
  const int b = blockIdx.x / GROUPS;
  const int g = blockIdx.x % GROUPS;
  const int Cg = C / GROUPS;
  const size_t base = ((size_t)b * C + (size_t)g * Cg) * Tn;
  const int M = Cg * Tn;
  const int tid = threadIdx.x;

  float sum = 0.f, ss = 0.f;
  for (int i = tid * 4; i < M; i += 256 * 4) {
    float4 v = *(const float4*)(x + base + i);
    sum += v.x + v.y + v.z + v.w;
    ss  += v.x * v.x + v.y * v.y + v.z * v.z + v.w * v.w;
  }
#pragma unroll
  for (int off = 32; off > 0; off >>= 1) {
    sum += __shfl_down(sum, off);
    ss  += __shfl_down(ss, off);
  }
  __shared__ float s1[4], s2[4];
  __shared__ float smean, sinv;
  const int wid = tid >> 6, lane = tid & 63;
  if (lane == 0) { s1[wid] = sum; s2[wid] = ss; }
  __syncthreads();
  if (tid == 0) {
    float t1 = s1[0] + s1[1] + s1[2] + s1[3];
    float t2 = s2[0] + s2[1] + s2[2] + s2[3];
    float mean = t1 / (float)M;
    float var  = t2 / (float)M - mean * mean;
    smean = mean;
    sinv  = rsqrtf(var + EPS_GN);
  }
  __syncthreads();
  const float mean = smean, inv = sinv;
  for (int i = tid * 4; i < M; i += 256 * 4) {
    float4 v = *(const float4*)(x + base + i);
    const int ch = g * Cg + (i >> tshift);
    const float sc = gamma[ch] * inv;
    const float sh = beta[ch] - mean * sc;
    v.x = fmaxf(v.x * sc + sh, 0.f);
    v.y = fmaxf(v.y * sc + sh, 0.f);
    v.z = fmaxf(v.z * sc + sh, 0.f);
    v.w = fmaxf(v.w * sc + sh, 0.f);
    *(float4*)(x + base + i) = v;
  }
}

extern "C" void kernel_launch(void* const* d_in, const int* in_sizes, int n_in,
                              void* d_out, int out_size, void* d_ws, size_t ws_size,
                              hipStream_t stream)
{
  (void)in_sizes; (void)n_in; (void)out_size; (void)ws_size;

  const float* feature  = (const float*)d_in[0];   // [4,512,2048]
  const float* frame    = (const float*)d_in[1];   // [4,256,4096]
  const float* segments = (const float*)d_in[2];   // [4,2048,4]
  const float* fsegs    = (const float*)d_in[3];   // [4,2048,4]
  const float* flc      = (const float*)d_in[4];   // [4,250,2048]
  const float* conf     = (const float*)d_in[5];   // [4,250,2048]
  const float* w_cur  = (const float*)d_in[6];
  const float* b_cur  = (const float*)d_in[7];
  const float* g_cur  = (const float*)d_in[8];
  const float* be_cur = (const float*)d_in[9];
  const float* w_lr   = (const float*)d_in[10];
  const float* b_lr   = (const float*)d_in[11];
  const float* g_lr   = (const float*)d_in[12];
  const float* be_lr  = (const float*)d_in[13];
  const float* w_roi  = (const float*)d_in[14];
  const float* b_roi  = (const float*)d_in[15];
  const float* g_roi  = (const float*)d_in[16];
  const float* be_roi = (const float*)d_in[17];
  const float* w_prop = (const float*)d_in[18];
  const float* b_prop = (const float*)d_in[19];
  const float* g_prop = (const float*)d_in[20];
  const float* be_prop= (const float*)d_in[21];

  // Outputs are FLOAT32: [out0 | feat], 4*512*2048 each.
  float* OUT0 = (float*)d_out;
  float* FOUT = (float*)d_out + 4194304;

  // ---- workspace layout ----
  float* ws  = (float*)d_ws;
  float* Y1  = ws;                 // fm_short  f32  4*256*2048
  float* RF  = Y1 + 2097152;       // roi block f32  4*256*2048
  ushort* U    = (ushort*)(RF + 2097152);
  ushort* FT   = U;                 // feature_t, then feat_t [4][2048][512]
  ushort* FRT  = FT + 4194304;      // frame_t   [4][4096][256]
  ushort* BX8F = FRT + 4194304;     // 8-block max feat_t  [4][256][512]
  ushort* BX32F= BX8F + 524288;     // 32-block max feat_t [4][64][512]
  ushort* BX8R = BX32F + 131072;    // 8-block max frame_t [4][512][256]
  ushort* BX32R= BX8R + 524288;     // 32-block max frame_t[4][128][256]
  ushort* RPT  = BX32R + 131072;    // roi pooled bf16 [4][2048][256]
  ushort* CATT = RPT + 2097152;     // cat_t [4][2048][1536]
  ushort* WCB  = CATT + 12582912;   // w_cur  bf16 [256][512]
  ushort* WLB  = WCB + 131072;      // w_lr   bf16 [512][512]
  ushort* WRB  = WLB + 262144;      // w_roi  bf16 [256][256]
  ushort* WPB  = WRB + 65536;       // w_prop bf16 [512][1536] padded
  // total ~68 MB

  // ---- weight casts ----
  cast_w_kernel<<<dim3(512),  256, 0, stream>>>(w_cur,  WCB, 512, 512, 131072);
  cast_w_kernel<<<dim3(1024), 256, 0, stream>>>(w_lr,   WLB, 512, 512, 262144);
  cast_w_kernel<<<dim3(256),  256, 0, stream>>>(w_roi,  WRB, 256, 256, 65536);
  cast_w_kernel<<<dim3(3072), 256, 0, stream>>>(w_prop, WPB, 1524, 1536, 786432);

  // ---- feature -> feature_t ----
  transpose_cast_off<<<dim3(64, 16, 4), 256, 0, stream>>>(feature, FT, 512, 2048, 512, 0, 512);

  // 1) fm_short = relu(GN(conv(feature, w_cur)))
  mfma_gemm<<<dim3(16, 2, 4), 256, 0, stream>>>(WCB, FT, b_cur, Y1, 256, 512, 2048);
  gn_relu_inplace<<<dim3(128), 256, 0, stream>>>(Y1, g_cur, be_cur, 256, 2048, 11);

  // 2) feat = relu(GN(conv(feature, w_lr)))  -> output 1
  mfma_gemm<<<dim3(16, 4, 4), 256, 0, stream>>>(WLB, FT, b_lr, FOUT, 512, 512, 2048);
  gn_relu_inplace<<<dim3(128), 256, 0, stream>>>(FOUT, g_lr, be_lr, 512, 2048, 11);

  // 3) feat -> feat_t (reuse FT); 2-level blockmax; pool into CATT[.,.,256:768)
  transpose_cast_off<<<dim3(64, 16, 4), 256, 0, stream>>>(FOUT, FT, 512, 2048, 512, 0, 512);
  bmx_reduce<<<dim3(256), 256, 0, stream>>>(FT,   BX8F,  512, 8, 65536);
  bmx_reduce<<<dim3(64),  256, 0, stream>>>(BX8F, BX32F, 512, 4, 16384);
  pool_t_kernel<4><<<dim3(512, 2, 4), 256, 0, stream>>>(
      FT, BX32F, BX8F, segments, CATT, 512, 2048, 64, 256, 2048, 1536, 256);

  // 4) frame -> frame_t; 2-level blockmax; pool into RPT
  transpose_cast_off<<<dim3(128, 8, 4), 256, 0, stream>>>(frame, FRT, 256, 4096, 256, 0, 256);
  bmx_reduce<<<dim3(256), 256, 0, stream>>>(FRT,  BX8R,  256, 8, 65536);
  bmx_reduce<<<dim3(64),  256, 0, stream>>>(BX8R, BX32R, 256, 4, 16384);
  pool_t_kernel<2><<<dim3(512, 2, 4), 256, 0, stream>>>(
      FRT, BX32R, BX8R, fsegs, RPT, 256, 4096, 128, 512, 2048, 256, 0);

  // 5) prop_roi = relu(GN(conv(roi_pooled, w_roi)))
  mfma_gemm<<<dim3(16, 2, 4), 256, 0, stream>>>(WRB, RPT, b_roi, RF, 256, 256, 2048);
  gn_relu_inplace<<<dim3(128), 256, 0, stream>>>(RF, g_roi, be_roi, 256, 2048, 11);

  // 6) remaining cat slices: RF(0:256), Y1(768:1024), flc(1024:1274), conf(1274:1536 w/ pad)
  transpose_cast_off<<<dim3(64, 8, 4), 256, 0, stream>>>(RF,  CATT, 256, 2048, 1536, 0,    256);
  transpose_cast_off<<<dim3(64, 8, 4), 256, 0, stream>>>(Y1,  CATT, 256, 2048, 1536, 768,  256);
  transpose_cast_off<<<dim3(64, 8, 4), 256, 0, stream>>>(flc, CATT, 250, 2048, 1536, 1024, 250);
  transpose_cast_off<<<dim3(64, 9, 4), 256, 0, stream>>>(conf,CATT, 250, 2048, 1536, 1274, 262);

  // 7) out0 = relu(GN(conv(cat, w_prop)))
  mfma_gemm<<<dim3(16, 4, 4), 256, 0, stream>>>(WPB, CATT, b_prop, OUT0, 512, 1536, 2048);
  gn_relu_inplace<<<dim3(128), 256, 0, stream>>>(OUT0, g_prop, be_prop, 512, 2048, 11);
}

// Round 12
// 431.012 us; speedup vs baseline: 1.0013x; 1.0013x over previous
//
#include <hip/hip_runtime.h>
#include <hip/hip_bf16.h>

#define GROUPS 32
#define EPS_GN 1e-5f

typedef short bf16x8 __attribute__((ext_vector_type(8)));
typedef float f32x4 __attribute__((ext_vector_type(4)));

__device__ __forceinline__ ushort to_bf16_bits(float v) {
  __hip_bfloat16 h = __float2bfloat16(v);
  return *(ushort*)&h;
}
__device__ __forceinline__ float bflo(unsigned u) { return __uint_as_float(u << 16); }
__device__ __forceinline__ float bfhi(unsigned u) { return __uint_as_float(u & 0xffff0000u); }
__device__ __forceinline__ ushort bfpack(float f) {
  return (ushort)(__float_as_uint(f) >> 16);   // exact: values originate from bf16
}

// ---------------- weight cast f32 [O][K] -> bf16 [O][Kp] (zero pad K..Kp) --------
__global__ __launch_bounds__(256)
void cast_w_kernel(const float* __restrict__ w, ushort* __restrict__ wb,
                   int K, int Kp, int total)
{
  int idx = blockIdx.x * 256 + threadIdx.x;
  if (idx >= total) return;
  int o = idx / Kp, k = idx - o * Kp;
  float v = (k < K) ? w[(size_t)o * K + k] : 0.f;
  wb[idx] = to_bf16_bits(v);
}

// ------- transpose+cast with offset: f32 [B][C][T] -> bf16 dst[b][t][coff+c] -----
__global__ __launch_bounds__(256)
void transpose_cast_off(const float* __restrict__ src, ushort* __restrict__ dst,
                        int C, int T, int dstride, int coff, int Cpad)
{
  __shared__ float tile[32][33];
  const int b = blockIdx.z;
  const int c0 = blockIdx.y * 32, t0 = blockIdx.x * 32;
  const int tx = threadIdx.x & 31, ty = threadIdx.x >> 5;   // 32 x 8
#pragma unroll
  for (int i = 0; i < 4; ++i) {
    const int c = c0 + ty + 8 * i;
    tile[ty + 8 * i][tx] = (c < C) ? src[((size_t)b * C + c) * T + t0 + tx] : 0.f;
  }
  __syncthreads();
  const int cw = c0 + tx;
  if (cw >= Cpad) return;
#pragma unroll
  for (int i = 0; i < 4; ++i)
    dst[((size_t)b * T + t0 + ty + 8 * i) * dstride + coff + cw] =
        to_bf16_bits(tile[tx][ty + 8 * i]);
}

// ---- generic row-group maxima: dst[rt][c] = max over `rows` consecutive src rows --
__global__ __launch_bounds__(256)
void bmx_reduce(const ushort* __restrict__ src, ushort* __restrict__ dst,
                int C, int rows, int total8)
{
  int idx = blockIdx.x * 256 + threadIdx.x;
  if (idx >= total8) return;
  const int nc8 = C >> 3;
  const int ci = idx % nc8;
  const int rt = idx / nc8;
  const ushort* p = src + (size_t)rt * rows * C + ci * 8;
  float m[8];
#pragma unroll
  for (int i = 0; i < 8; ++i) m[i] = -3.402823466e38f;
  for (int j = 0; j < rows; ++j) {
    const uint4 v = *(const uint4*)(p + (size_t)j * C);
    m[0] = fmaxf(m[0], bflo(v.x)); m[1] = fmaxf(m[1], bfhi(v.x));
    m[2] = fmaxf(m[2], bflo(v.y)); m[3] = fmaxf(m[3], bfhi(v.y));
    m[4] = fmaxf(m[4], bflo(v.z)); m[5] = fmaxf(m[5], bfhi(v.z));
    m[6] = fmaxf(m[6], bflo(v.w)); m[7] = fmaxf(m[7], bfhi(v.w));
  }
  uint4 o;
  o.x = (unsigned)bfpack(m[0]) | ((unsigned)bfpack(m[1]) << 16);
  o.y = (unsigned)bfpack(m[2]) | ((unsigned)bfpack(m[3]) << 16);
  o.z = (unsigned)bfpack(m[4]) | ((unsigned)bfpack(m[5]) << 16);
  o.w = (unsigned)bfpack(m[6]) | ((unsigned)bfpack(m[7]) << 16);
  *(uint4*)(dst + (size_t)rt * C + ci * 8) = o;
}

// ------- transposed boundary max pool with 2-level tables (8- and 32-blocks) ------
template<int CHL>
__global__ __launch_bounds__(256)
void pool_t_kernel(const ushort* __restrict__ xt, const ushort* __restrict__ bx32,
                   const ushort* __restrict__ bx8, const float* __restrict__ segs,
                   ushort* __restrict__ dst,
                   int C, int T, int TB32, int TB8, int N, int dstride, int coff)
{
  const int b    = blockIdx.z;
  const int half = blockIdx.y;
  const int n    = blockIdx.x * 4 + (threadIdx.x >> 6);
  const int lane = threadIdx.x & 63;
  const int c    = half * (C >> 1) + lane * CHL;

  const float4 sg = *(const float4*)(segs + ((size_t)b * N + n) * 4);
  const float f0 = half ? sg.z : sg.x;
  const float f1 = half ? sg.w : sg.y;
  int s = min(max((int)floorf(f0), 0), T - 1);
  int e = min(max((int)ceilf(f1), 0), T - 1);
  e = max(e, s);

  const ushort* xp  = xt  + (size_t)b * T    * C + c;
  const ushort* bp  = bx32+ (size_t)b * TB32 * C + c;
  const ushort* b8p = bx8 + (size_t)b * TB8  * C + c;

  float m[4][CHL];
#pragma unroll
  for (int u = 0; u < 4; ++u)
#pragma unroll
    for (int i = 0; i < CHL; ++i) m[u][i] = -3.402823466e38f;

  auto acc1 = [&](float* mm, const ushort* p) {
    if constexpr (CHL == 4) {
      const uint2 v = *(const uint2*)p;
      mm[0] = fmaxf(mm[0], bflo(v.x)); mm[1] = fmaxf(mm[1], bfhi(v.x));
      mm[2] = fmaxf(mm[2], bflo(v.y)); mm[3] = fmaxf(mm[3], bfhi(v.y));
    } else {
      const unsigned v = *(const unsigned*)p;
      mm[0] = fmaxf(mm[0], bflo(v)); mm[1] = fmaxf(mm[1], bfhi(v));
    }
  };
  auto scan = [&](const ushort* p, int cnt) {
    int i = 0;
    for (; i + 4 <= cnt; i += 4) {
      acc1(m[0], p);
      acc1(m[1], p + (size_t)C);
      acc1(m[2], p + 2 * (size_t)C);
      acc1(m[3], p + 3 * (size_t)C);
      p += 4 * (size_t)C;
    }
    for (; i < cnt; ++i) { acc1(m[0], p); p += (size_t)C; }
  };

  const int b0 = s >> 5, b1 = e >> 5;
  if (b0 == b1) {
    scan(xp + (size_t)s * C, e - s + 1);
  } else {
    const int t0e = (b0 + 1) << 5;
    const int a8 = (s + 7) & ~7;
    scan(xp + (size_t)s * C, a8 - s);
    scan(b8p + (size_t)(a8 >> 3) * C, (t0e - a8) >> 3);
    scan(bp + (size_t)(b0 + 1) * C, b1 - b0 - 1);
    const int r0 = b1 << 5;
    const int cnt8 = ((e + 1) >> 3) - (r0 >> 3);
    scan(b8p + (size_t)(r0 >> 3) * C, cnt8);
    const int ts = r0 + (cnt8 << 3);
    scan(xp + (size_t)ts * C, e - ts + 1);
  }

#pragma unroll
  for (int i = 0; i < CHL; ++i)
    m[0][i] = fmaxf(fmaxf(m[0][i], m[1][i]), fmaxf(m[2][i], m[3][i]));

  ushort* op = dst + ((size_t)b * N + n) * dstride + coff + c;
  if constexpr (CHL == 4) {
    uint2 o;
    o.x = (unsigned)bfpack(m[0][0]) | ((unsigned)bfpack(m[0][1]) << 16);
    o.y = (unsigned)bfpack(m[0][2]) | ((unsigned)bfpack(m[0][3]) << 16);
    *(uint2*)op = o;
  } else {
    *(unsigned*)op = (unsigned)bfpack(m[0][0]) | ((unsigned)bfpack(m[0][1]) << 16);
  }
}

// ---------------- bf16 MFMA GEMM: out[b,o,t] = sum_k W[o,k]*Xt[b,t,k] + bias[o] --
// block 256 thr = 4 waves stacked along O; block tile 128(O) x 64(T);
// wave tile 32(O) x 64(T): 2 A-frags, 4 B-frags, 8 MFMAs / 32-k step.
// Grid (T/64, O/128, B) -> big GEMMs get 512 blocks = 2 blocks/CU (TLP).
__global__ __launch_bounds__(256)
void mfma_gemm(const ushort* __restrict__ Wb, const ushort* __restrict__ Xt,
               const float* __restrict__ bias, float* __restrict__ out,
               int O, int K, int T)
{
  const int b  = blockIdx.z;
  const int t0 = blockIdx.x * 64;
  const int o0 = blockIdx.y * 128 + (threadIdx.x >> 6) * 32;  // wave's O base
  const int lane = threadIdx.x & 63;
  const int lr = lane & 15;
  const int lq = lane >> 4;

  const ushort* wp = Wb + (size_t)(o0 + lr) * K + lq * 8;
  const ushort* xp = Xt + ((size_t)b * T + t0 + lr) * K + lq * 8;

  f32x4 acc[2][4];
#pragma unroll
  for (int i = 0; i < 2; ++i)
#pragma unroll
    for (int j = 0; j < 4; ++j) acc[i][j] = (f32x4){0.f, 0.f, 0.f, 0.f};

  for (int k0 = 0; k0 < K; k0 += 32) {
    bf16x8 a[2], bt[4];
#pragma unroll
    for (int i = 0; i < 2; ++i)
      a[i] = *(const bf16x8*)(wp + (size_t)i * 16 * K + k0);
#pragma unroll
    for (int j = 0; j < 4; ++j)
      bt[j] = *(const bf16x8*)(xp + (size_t)j * 16 * K + k0);
#pragma unroll
    for (int i = 0; i < 2; ++i)
#pragma unroll
      for (int j = 0; j < 4; ++j)
        acc[i][j] = __builtin_amdgcn_mfma_f32_16x16x32_bf16(a[i], bt[j], acc[i][j], 0, 0, 0);
  }

#pragma unroll
  for (int i = 0; i < 2; ++i) {
#pragma unroll
    for (int r = 0; r < 4; ++r) {
      const int o = o0 + i * 16 + lq * 4 + r;
      const float bs = bias[o];
      float* op = out + ((size_t)b * O + o) * T + t0 + lr;
#pragma unroll
      for (int j = 0; j < 4; ++j) op[j * 16] = acc[i][j][r] + bs;
    }
  }
}

// ---------------- GroupNorm(+ReLU) in-place over [B,C,Tn] ------------------------
__global__ __launch_bounds__(256)
void gn_relu_inplace(float* __restrict__ x, const float* __restrict__ gamma,
                     const float* __restrict__ beta, int C, int Tn, int tshift)
{
  const int b = blockIdx.x / GROUPS;
  const int g = blockIdx.x % GROUPS;
  const int Cg = C / GROUPS;
  const size_t base = ((size_t)b * C + (size_t)g * Cg) * Tn;
  const int M = Cg * Tn;
  const int tid = threadIdx.x;

  float sum = 0.f, ss = 0.f;
  for (int i = tid * 4; i < M; i += 256 * 4) {
    float4 v = *(const float4*)(x + base + i);
    sum += v.x + v.y + v.z + v.w;
    ss  += v.x * v.x + v.y * v.y + v.z * v.z + v.w * v.w;
  }
#pragma unroll
  for (int off = 32; off > 0; off >>= 1) {
    sum += __shfl_down(sum, off);
    ss  += __shfl_down(ss, off);
  }
  __shared__ float s1[4], s2[4];
  __shared__ float smean, sinv;
  const int wid = tid >> 6, lane = tid & 63;
  if (lane == 0) { s1[wid] = sum; s2[wid] = ss; }
  __syncthreads();
  if (tid == 0) {
    float t1 = s1[0] + s1[1] + s1[2] + s1[3];
    float t2 = s2[0] + s2[1] + s2[2] + s2[3];
    float mean = t1 / (float)M;
    float var  = t2 / (float)M - mean * mean;
    smean = mean;
    sinv  = rsqrtf(var + EPS_GN);
  }
  __syncthreads();
  const float mean = smean, inv = sinv;
  for (int i = tid * 4; i < M; i += 256 * 4) {
    float4 v = *(const float4*)(x + base + i);
    const int ch = g * Cg + (i >> tshift);
    const float sc = gamma[ch] * inv;
    const float sh = beta[ch] - mean * sc;
    v.x = fmaxf(v.x * sc + sh, 0.f);
    v.y = fmaxf(v.y * sc + sh, 0.f);
    v.z = fmaxf(v.z * sc + sh, 0.f);
    v.w = fmaxf(v.w * sc + sh, 0.f);
    *(float4*)(x + base + i) = v;
  }
}

extern "C" void kernel_launch(void* const* d_in, const int* in_sizes, int n_in,
                              void* d_out, int out_size, void* d_ws, size_t ws_size,
                              hipStream_t stream)
{
  (void)in_sizes; (void)n_in; (void)out_size; (void)ws_size;

  const float* feature  = (const float*)d_in[0];   // [4,512,2048]
  const float* frame    = (const float*)d_in[1];   // [4,256,4096]
  const float* segments = (const float*)d_in[2];   // [4,2048,4]
  const float* fsegs    = (const float*)d_in[3];   // [4,2048,4]
  const float* flc      = (const float*)d_in[4];   // [4,250,2048]
  const float* conf     = (const float*)d_in[5];   // [4,250,2048]
  const float* w_cur  = (const float*)d_in[6];
  const float* b_cur  = (const float*)d_in[7];
  const float* g_cur  = (const float*)d_in[8];
  const float* be_cur = (const float*)d_in[9];
  const float* w_lr   = (const float*)d_in[10];
  const float* b_lr   = (const float*)d_in[11];
  const float* g_lr   = (const float*)d_in[12];
  const float* be_lr  = (const float*)d_in[13];
  const float* w_roi  = (const float*)d_in[14];
  const float* b_roi  = (const float*)d_in[15];
  const float* g_roi  = (const float*)d_in[16];
  const float* be_roi = (const float*)d_in[17];
  const float* w_prop = (const float*)d_in[18];
  const float* b_prop = (const float*)d_in[19];
  const float* g_prop = (const float*)d_in[20];
  const float* be_prop= (const float*)d_in[21];

  // Outputs are FLOAT32: [out0 | feat], 4*512*2048 each.
  float* OUT0 = (float*)d_out;
  float* FOUT = (float*)d_out + 4194304;

  // ---- workspace layout ----
  float* ws  = (float*)d_ws;
  float* Y1  = ws;                 // fm_short  f32  4*256*2048
  float* RF  = Y1 + 2097152;       // roi block f32  4*256*2048
  ushort* U    = (ushort*)(RF + 2097152);
  ushort* FT   = U;                 // feature_t, then feat_t [4][2048][512]
  ushort* FRT  = FT + 4194304;      // frame_t   [4][4096][256]
  ushort* BX8F = FRT + 4194304;     // 8-block max feat_t  [4][256][512]
  ushort* BX32F= BX8F + 524288;     // 32-block max feat_t [4][64][512]
  ushort* BX8R = BX32F + 131072;    // 8-block max frame_t [4][512][256]
  ushort* BX32R= BX8R + 524288;     // 32-block max frame_t[4][128][256]
  ushort* RPT  = BX32R + 131072;    // roi pooled bf16 [4][2048][256]
  ushort* CATT = RPT + 2097152;     // cat_t [4][2048][1536]
  ushort* WCB  = CATT + 12582912;   // w_cur  bf16 [256][512]
  ushort* WLB  = WCB + 131072;      // w_lr   bf16 [512][512]
  ushort* WRB  = WLB + 262144;      // w_roi  bf16 [256][256]
  ushort* WPB  = WRB + 65536;       // w_prop bf16 [512][1536] padded
  // total ~68 MB

  // ---- weight casts ----
  cast_w_kernel<<<dim3(512),  256, 0, stream>>>(w_cur,  WCB, 512, 512, 131072);
  cast_w_kernel<<<dim3(1024), 256, 0, stream>>>(w_lr,   WLB, 512, 512, 262144);
  cast_w_kernel<<<dim3(256),  256, 0, stream>>>(w_roi,  WRB, 256, 256, 65536);
  cast_w_kernel<<<dim3(3072), 256, 0, stream>>>(w_prop, WPB, 1524, 1536, 786432);

  // ---- feature -> feature_t ----
  transpose_cast_off<<<dim3(64, 16, 4), 256, 0, stream>>>(feature, FT, 512, 2048, 512, 0, 512);

  // 1) fm_short = relu(GN(conv(feature, w_cur)))      grid (32,2,4)=256
  mfma_gemm<<<dim3(32, 2, 4), 256, 0, stream>>>(WCB, FT, b_cur, Y1, 256, 512, 2048);
  gn_relu_inplace<<<dim3(128), 256, 0, stream>>>(Y1, g_cur, be_cur, 256, 2048, 11);

  // 2) feat = relu(GN(conv(feature, w_lr)))  -> output 1   grid (32,4,4)=512
  mfma_gemm<<<dim3(32, 4, 4), 256, 0, stream>>>(WLB, FT, b_lr, FOUT, 512, 512, 2048);
  gn_relu_inplace<<<dim3(128), 256, 0, stream>>>(FOUT, g_lr, be_lr, 512, 2048, 11);

  // 3) feat -> feat_t (reuse FT); 2-level blockmax; pool into CATT[.,.,256:768)
  transpose_cast_off<<<dim3(64, 16, 4), 256, 0, stream>>>(FOUT, FT, 512, 2048, 512, 0, 512);
  bmx_reduce<<<dim3(256), 256, 0, stream>>>(FT,   BX8F,  512, 8, 65536);
  bmx_reduce<<<dim3(64),  256, 0, stream>>>(BX8F, BX32F, 512, 4, 16384);
  pool_t_kernel<4><<<dim3(512, 2, 4), 256, 0, stream>>>(
      FT, BX32F, BX8F, segments, CATT, 512, 2048, 64, 256, 2048, 1536, 256);

  // 4) frame -> frame_t; 2-level blockmax; pool into RPT
  transpose_cast_off<<<dim3(128, 8, 4), 256, 0, stream>>>(frame, FRT, 256, 4096, 256, 0, 256);
  bmx_reduce<<<dim3(256), 256, 0, stream>>>(FRT,  BX8R,  256, 8, 65536);
  bmx_reduce<<<dim3(64),  256, 0, stream>>>(BX8R, BX32R, 256, 4, 16384);
  pool_t_kernel<2><<<dim3(512, 2, 4), 256, 0, stream>>>(
      FRT, BX32R, BX8R, fsegs, RPT, 256, 4096, 128, 512, 2048, 256, 0);

  // 5) prop_roi = relu(GN(conv(roi_pooled, w_roi)))   grid (32,2,4)=256
  mfma_gemm<<<dim3(32, 2, 4), 256, 0, stream>>>(WRB, RPT, b_roi, RF, 256, 256, 2048);
  gn_relu_inplace<<<dim3(128), 256, 0, stream>>>(RF, g_roi, be_roi, 256, 2048, 11);

  // 6) remaining cat slices: RF(0:256), Y1(768:1024), flc(1024:1274), conf(1274:1536 w/ pad)
  transpose_cast_off<<<dim3(64, 8, 4), 256, 0, stream>>>(RF,  CATT, 256, 2048, 1536, 0,    256);
  transpose_cast_off<<<dim3(64, 8, 4), 256, 0, stream>>>(Y1,  CATT, 256, 2048, 1536, 768,  256);
  transpose_cast_off<<<dim3(64, 8, 4), 256, 0, stream>>>(flc, CATT, 250, 2048, 1536, 1024, 250);
  transpose_cast_off<<<dim3(64, 9, 4), 256, 0, stream>>>(conf,CATT, 250, 2048, 1536, 1274, 262);

  // 7) out0 = relu(GN(conv(cat, w_prop)))   grid (32,4,4)=512
  mfma_gemm<<<dim3(32, 4, 4), 256, 0, stream>>>(WPB, CATT, b_prop, OUT0, 512, 1536, 2048);
  gn_relu_inplace<<<dim3(128), 256, 0, stream>>>(OUT0, g_prop, be_prop, 512, 2048, 11);
}